// Round 1
// baseline (245.513 us; speedup 1.0000x reference)
//
#include <hip/hip_runtime.h>

// Problem constants (from reference setup_inputs)
constexpr int B_ = 2, C_ = 256, H_ = 200, W_ = 200;
constexpr int N_ROIS = 512;
constexpr int OUT_H_ = 7, OUT_W_ = 7;
constexpr float SPATIAL_SCALE_ = 0.25f;
constexpr int NBIN = OUT_H_ * OUT_W_;   // 49

// ---------------------------------------------------------------------------
// Kernel 1: transpose (B, C, H, W) -> (B, H*W, C)   (channels-last)
// Classic LDS-tiled transpose, 32x32 tiles, block (32,8).
// H*W = 40000 and C = 256 are both multiples of 32 -> no bounds checks.
// ---------------------------------------------------------------------------
__global__ __launch_bounds__(256) void transpose_cl_kernel(
    const float* __restrict__ in, float* __restrict__ out) {
    __shared__ float tile[32][33];
    const int b  = blockIdx.z;
    const int p0 = blockIdx.x * 32;   // pixel tile origin
    const int c0 = blockIdx.y * 32;   // channel tile origin
    const int tx = threadIdx.x;       // 0..31
    const int ty = threadIdx.y;       // 0..7

    const float* src = in  + (size_t)b * C_ * H_ * W_;
    float*       dst = out + (size_t)b * H_ * W_ * C_;

#pragma unroll
    for (int j = 0; j < 32; j += 8) {
        tile[ty + j][tx] = src[(size_t)(c0 + ty + j) * (H_ * W_) + (p0 + tx)];
    }
    __syncthreads();
#pragma unroll
    for (int j = 0; j < 32; j += 8) {
        dst[(size_t)(p0 + ty + j) * C_ + (c0 + tx)] = tile[tx][ty + j];
    }
}

// ---------------------------------------------------------------------------
// Kernel 2: rotated ROI align gather.
// One 64-thread block per (n, ph, pw). Lane t owns channels [4t, 4t+4).
// CL = true  : feat is channels-last (B, H, W, C)  -> float4 coalesced loads
// CL = false : feat is channels-first (B, C, H, W) -> scalar fallback
// ---------------------------------------------------------------------------
template <bool CL>
__global__ __launch_bounds__(64) void rroi_align_kernel(
    const float* __restrict__ feat,
    const float* __restrict__ rois,
    float* __restrict__ out) {
    const int blk = blockIdx.x;          // n * 49 + bin
    const int n   = blk / NBIN;
    const int bin = blk % NBIN;
    const int ph  = bin / OUT_W_;
    const int pw  = bin % OUT_W_;

    const float* roi = rois + (size_t)n * 6;
    const int   b     = (int)roi[0];
    const float cx    = roi[1] * SPATIAL_SCALE_;
    const float cy    = roi[2] * SPATIAL_SCALE_;
    const float rw    = fmaxf(roi[3] * SPATIAL_SCALE_, 1.0f);
    const float rh    = fmaxf(roi[4] * SPATIAL_SCALE_, 1.0f);
    const float theta = roi[5];

    const float bin_h = rh / (float)OUT_H_;
    const float bin_w = rw / (float)OUT_W_;
    const float cosT  = cosf(theta);
    const float sinT  = sinf(theta);

    const int t = threadIdx.x;           // 0..63

    float4 acc = make_float4(0.f, 0.f, 0.f, 0.f);

#pragma unroll
    for (int s1 = 0; s1 < 2; ++s1) {
        const float yy = -rh * 0.5f + ((float)ph + ((float)s1 + 0.5f) * 0.5f) * bin_h;
#pragma unroll
        for (int s2 = 0; s2 < 2; ++s2) {
            const float xx = -rw * 0.5f + ((float)pw + ((float)s2 + 0.5f) * 0.5f) * bin_w;

            float x = xx * cosT + yy * sinT + cx;
            float y = yy * cosT - xx * sinT + cy;

            const bool valid = (y > -1.0f) && (y < (float)H_) &&
                               (x > -1.0f) && (x < (float)W_);
            if (!valid) continue;        // contributes 0 to the mean

            y = fminf(fmaxf(y, 0.0f), (float)(H_ - 1));
            x = fminf(fmaxf(x, 0.0f), (float)(W_ - 1));

            int y0 = (int)floorf(y);  if (y0 > H_ - 2) y0 = H_ - 2;
            int x0 = (int)floorf(x);  if (x0 > W_ - 2) x0 = W_ - 2;

            const float ly = y - (float)y0;
            const float lx = x - (float)x0;
            const float hy = 1.0f - ly;
            const float hx = 1.0f - lx;
            const float w00 = hy * hx, w01 = hy * lx;
            const float w10 = ly * hx, w11 = ly * lx;

            if (CL) {
                const float* base = feat + (size_t)b * H_ * W_ * C_;
                const float* r0 = base + ((size_t)y0 * W_ + x0) * C_;
                const float* r1 = base + ((size_t)(y0 + 1) * W_ + x0) * C_;
                const float4 f00 = *((const float4*)r0 + t);
                const float4 f01 = *((const float4*)(r0 + C_) + t);
                const float4 f10 = *((const float4*)r1 + t);
                const float4 f11 = *((const float4*)(r1 + C_) + t);
                acc.x += w00 * f00.x + w01 * f01.x + w10 * f10.x + w11 * f11.x;
                acc.y += w00 * f00.y + w01 * f01.y + w10 * f10.y + w11 * f11.y;
                acc.z += w00 * f00.z + w01 * f01.z + w10 * f10.z + w11 * f11.z;
                acc.w += w00 * f00.w + w01 * f01.w + w10 * f10.w + w11 * f11.w;
            } else {
                const int off0 = y0 * W_ + x0;
                float vals[4];
#pragma unroll
                for (int i = 0; i < 4; ++i) {
                    const int c = 4 * t + i;
                    const float* base = feat + ((size_t)b * C_ + c) * (H_ * W_);
                    vals[i] = w00 * base[off0] + w01 * base[off0 + 1] +
                              w10 * base[off0 + W_] + w11 * base[off0 + W_ + 1];
                }
                acc.x += vals[0]; acc.y += vals[1]; acc.z += vals[2]; acc.w += vals[3];
            }
        }
    }

    // mean over SAMPLE_NUM*SAMPLE_NUM = 4 (invalid samples count as zero)
    const float inv = 0.25f;
    float res[4] = {acc.x * inv, acc.y * inv, acc.z * inv, acc.w * inv};

    // out layout: (N, C, OUT_H, OUT_W) -> index ((n*C + c)*49 + bin)
#pragma unroll
    for (int i = 0; i < 4; ++i) {
        out[((size_t)n * C_ + (4 * t + i)) * NBIN + bin] = res[i];
    }
}

extern "C" void kernel_launch(void* const* d_in, const int* in_sizes, int n_in,
                              void* d_out, int out_size, void* d_ws, size_t ws_size,
                              hipStream_t stream) {
    const float* features = (const float*)d_in[0];  // (B, C, H, W)
    const float* rois     = (const float*)d_in[1];  // (N, 6)
    float* out = (float*)d_out;                     // (N, C, 7, 7)

    const size_t need = (size_t)B_ * C_ * H_ * W_ * sizeof(float);
    if (ws_size >= need) {
        float* feat_cl = (float*)d_ws;
        dim3 tb(32, 8, 1);
        dim3 tg((H_ * W_) / 32, C_ / 32, B_);
        transpose_cl_kernel<<<tg, tb, 0, stream>>>(features, feat_cl);
        rroi_align_kernel<true><<<N_ROIS * NBIN, 64, 0, stream>>>(feat_cl, rois, out);
    } else {
        rroi_align_kernel<false><<<N_ROIS * NBIN, 64, 0, stream>>>(features, rois, out);
    }
}

// Round 2
// 180.604 us; speedup vs baseline: 1.3594x; 1.3594x over previous
//
#include <hip/hip_runtime.h>

// Problem constants (from reference setup_inputs)
constexpr int B_ = 2, C_ = 256, H_ = 200, W_ = 200;
constexpr int HW_ = H_ * W_;            // 40000
constexpr int N_ROIS = 512;
constexpr int OUT_H_ = 7, OUT_W_ = 7;
constexpr float SPATIAL_SCALE_ = 0.25f;
constexpr int NBIN = OUT_H_ * OUT_W_;   // 49
constexpr int OUT_PER_ROI = C_ * NBIN;  // 12544 floats

// ---------------------------------------------------------------------------
// Kernel 1: transpose (B, C, H, W) -> (B, H*W, C), float4 on both global sides.
// Tile: 64 pixels x 64 channels, block 256. HW % 64 == 0, C % 64 == 0.
// LDS tile[p][c], row pad to 68 floats (272 B = 17 x 16 B, float4-aligned).
// ---------------------------------------------------------------------------
__global__ __launch_bounds__(256) void transpose_cl_kernel(
    const float* __restrict__ in, float* __restrict__ out) {
    __shared__ float tile[64][68];
    const int b  = blockIdx.z;
    const int p0 = blockIdx.x * 64;   // pixel tile origin
    const int c0 = blockIdx.y * 64;   // channel tile origin
    const int tid = threadIdx.x;
    const int hi = tid >> 4;          // 0..15
    const int lo = tid & 15;          // 0..15

    const float* src = in  + (size_t)b * C_ * HW_;
    float*       dst = out + (size_t)b * HW_ * C_;

    // Load: lanes over pixels (coalesced float4), scatter into tile[p][c]
#pragma unroll
    for (int j = 0; j < 4; ++j) {
        const int cr = hi + j * 16;             // channel within tile
        const int pm = lo * 4;                  // pixel within tile
        const float4 v = *(const float4*)(src + (size_t)(c0 + cr) * HW_ + p0 + pm);
        tile[pm + 0][cr] = v.x;
        tile[pm + 1][cr] = v.y;
        tile[pm + 2][cr] = v.z;
        tile[pm + 3][cr] = v.w;
    }
    __syncthreads();
    // Store: lanes over channels (coalesced float4), read tile rows float4
#pragma unroll
    for (int j = 0; j < 4; ++j) {
        const int pr = hi + j * 16;             // pixel within tile
        const int cm = lo * 4;                  // channel within tile
        const float4 r = *(const float4*)&tile[pr][cm];
        *(float4*)(dst + (size_t)(p0 + pr) * C_ + c0 + cm) = r;
    }
}

// ---------------------------------------------------------------------------
// Kernel 2: rotated ROI align, one 256-thread block per ROI.
// Phase A: 196 threads compute sample offsets + premultiplied weights -> LDS.
// Phase B: wave w handles bins {w, w+4, ...}; lane owns 4 channels (float4);
//          4 corner loads are 1 KB coalesced reads from channels-last feat.
// Phase C: staged (C,49) result in LDS flushed float4-contiguous to global.
// ---------------------------------------------------------------------------
__global__ __launch_bounds__(256) void rroi_gather_kernel(
    const float* __restrict__ feat_cl,   // (B, H*W, C)
    const float* __restrict__ rois,
    float* __restrict__ out) {
    __shared__ float  s_out[OUT_PER_ROI];   // 50176 B, laid out [c][bin]
    __shared__ int    s_off[196];
    __shared__ float4 s_w[196];

    const int n   = blockIdx.x;
    const int tid = threadIdx.x;

    const float* roi = rois + (size_t)n * 6;
    const int   b     = (int)roi[0];
    const float cx    = roi[1] * SPATIAL_SCALE_;
    const float cy    = roi[2] * SPATIAL_SCALE_;
    const float rw    = fmaxf(roi[3] * SPATIAL_SCALE_, 1.0f);
    const float rh    = fmaxf(roi[4] * SPATIAL_SCALE_, 1.0f);
    const float theta = roi[5];
    const float bin_h = rh / (float)OUT_H_;
    const float bin_w = rw / (float)OUT_W_;

    if (tid < 196) {
        const float cosT = cosf(theta);
        const float sinT = sinf(theta);
        const int bin = tid >> 2;
        const int s   = tid & 3;
        const int ph  = bin / OUT_W_;
        const int pw  = bin - ph * OUT_W_;
        const int s1  = s >> 1;
        const int s2  = s & 1;

        const float yy = -rh * 0.5f + ((float)ph + ((float)s1 + 0.5f) * 0.5f) * bin_h;
        const float xx = -rw * 0.5f + ((float)pw + ((float)s2 + 0.5f) * 0.5f) * bin_w;

        float x = xx * cosT + yy * sinT + cx;
        float y = yy * cosT - xx * sinT + cy;

        const bool valid = (y > -1.0f) && (y < (float)H_) &&
                           (x > -1.0f) && (x < (float)W_);

        y = fminf(fmaxf(y, 0.0f), (float)(H_ - 1));
        x = fminf(fmaxf(x, 0.0f), (float)(W_ - 1));
        int y0 = (int)floorf(y);  if (y0 > H_ - 2) y0 = H_ - 2;
        int x0 = (int)floorf(x);  if (x0 > W_ - 2) x0 = W_ - 2;

        const float ly = y - (float)y0;
        const float lx = x - (float)x0;
        const float hy = 1.0f - ly;
        const float hx = 1.0f - lx;
        const float m  = valid ? 0.25f : 0.0f;   // fold mean + validity

        s_w[tid]   = make_float4(hy * hx * m, hy * lx * m, ly * hx * m, ly * lx * m);
        s_off[tid] = (y0 * W_ + x0) * C_;
    }
    __syncthreads();

    const int wave = tid >> 6;
    const int lane = tid & 63;
    const float* base = feat_cl + (size_t)b * HW_ * C_ + 4 * lane;

    for (int bin = wave; bin < NBIN; bin += 4) {
        float4 acc = make_float4(0.f, 0.f, 0.f, 0.f);
#pragma unroll
        for (int s = 0; s < 4; ++s) {
            const int j = bin * 4 + s;
            const int off = s_off[j];
            const float4 w = s_w[j];
            const float* p = base + off;
            const float4 f00 = *(const float4*)p;
            const float4 f01 = *(const float4*)(p + C_);
            const float4 f10 = *(const float4*)(p + W_ * C_);
            const float4 f11 = *(const float4*)(p + W_ * C_ + C_);
            acc.x += w.x * f00.x + w.y * f01.x + w.z * f10.x + w.w * f11.x;
            acc.y += w.x * f00.y + w.y * f01.y + w.z * f10.y + w.w * f11.y;
            acc.z += w.x * f00.z + w.y * f01.z + w.z * f10.z + w.w * f11.z;
            acc.w += w.x * f00.w + w.y * f01.w + w.z * f10.w + w.w * f11.w;
        }
        const int c = 4 * lane;
        s_out[(c + 0) * NBIN + bin] = acc.x;
        s_out[(c + 1) * NBIN + bin] = acc.y;
        s_out[(c + 2) * NBIN + bin] = acc.z;
        s_out[(c + 3) * NBIN + bin] = acc.w;
    }
    __syncthreads();

    // Flush: 12544 floats = 3136 float4 = 12*256 + 64
    float4* o = (float4*)(out + (size_t)n * OUT_PER_ROI);
    const float4* l = (const float4*)s_out;
#pragma unroll
    for (int k = 0; k < 12; ++k) {
        o[tid + 256 * k] = l[tid + 256 * k];
    }
    if (tid < 64) o[3072 + tid] = l[3072 + tid];
}

// ---------------------------------------------------------------------------
// Fallback (channels-first, scalar) — only if ws too small. One block per
// (n, bin), lane owns 4 channels.
// ---------------------------------------------------------------------------
__global__ __launch_bounds__(64) void rroi_fallback_kernel(
    const float* __restrict__ feat,
    const float* __restrict__ rois,
    float* __restrict__ out) {
    const int blk = blockIdx.x;
    const int n   = blk / NBIN;
    const int bin = blk % NBIN;
    const int ph  = bin / OUT_W_;
    const int pw  = bin % OUT_W_;

    const float* roi = rois + (size_t)n * 6;
    const int   b     = (int)roi[0];
    const float cx    = roi[1] * SPATIAL_SCALE_;
    const float cy    = roi[2] * SPATIAL_SCALE_;
    const float rw    = fmaxf(roi[3] * SPATIAL_SCALE_, 1.0f);
    const float rh    = fmaxf(roi[4] * SPATIAL_SCALE_, 1.0f);
    const float theta = roi[5];
    const float bin_h = rh / (float)OUT_H_;
    const float bin_w = rw / (float)OUT_W_;
    const float cosT  = cosf(theta);
    const float sinT  = sinf(theta);
    const int t = threadIdx.x;
    float acc[4] = {0.f, 0.f, 0.f, 0.f};

#pragma unroll
    for (int s1 = 0; s1 < 2; ++s1) {
        const float yy = -rh * 0.5f + ((float)ph + ((float)s1 + 0.5f) * 0.5f) * bin_h;
#pragma unroll
        for (int s2 = 0; s2 < 2; ++s2) {
            const float xx = -rw * 0.5f + ((float)pw + ((float)s2 + 0.5f) * 0.5f) * bin_w;
            float x = xx * cosT + yy * sinT + cx;
            float y = yy * cosT - xx * sinT + cy;
            const bool valid = (y > -1.0f) && (y < (float)H_) &&
                               (x > -1.0f) && (x < (float)W_);
            if (!valid) continue;
            y = fminf(fmaxf(y, 0.0f), (float)(H_ - 1));
            x = fminf(fmaxf(x, 0.0f), (float)(W_ - 1));
            int y0 = (int)floorf(y);  if (y0 > H_ - 2) y0 = H_ - 2;
            int x0 = (int)floorf(x);  if (x0 > W_ - 2) x0 = W_ - 2;
            const float ly = y - (float)y0, lx = x - (float)x0;
            const float hy = 1.0f - ly, hx = 1.0f - lx;
            const float w00 = hy * hx, w01 = hy * lx, w10 = ly * hx, w11 = ly * lx;
            const int off0 = y0 * W_ + x0;
#pragma unroll
            for (int i = 0; i < 4; ++i) {
                const float* base = feat + ((size_t)b * C_ + 4 * t + i) * HW_;
                acc[i] += w00 * base[off0] + w01 * base[off0 + 1] +
                          w10 * base[off0 + W_] + w11 * base[off0 + W_ + 1];
            }
        }
    }
#pragma unroll
    for (int i = 0; i < 4; ++i) {
        out[((size_t)n * C_ + (4 * t + i)) * NBIN + bin] = acc[i] * 0.25f;
    }
}

extern "C" void kernel_launch(void* const* d_in, const int* in_sizes, int n_in,
                              void* d_out, int out_size, void* d_ws, size_t ws_size,
                              hipStream_t stream) {
    const float* features = (const float*)d_in[0];  // (B, C, H, W)
    const float* rois     = (const float*)d_in[1];  // (N, 6)
    float* out = (float*)d_out;                     // (N, C, 7, 7)

    const size_t need = (size_t)B_ * C_ * HW_ * sizeof(float);
    if (ws_size >= need) {
        float* feat_cl = (float*)d_ws;
        dim3 tg(HW_ / 64, C_ / 64, B_);
        transpose_cl_kernel<<<tg, 256, 0, stream>>>(features, feat_cl);
        rroi_gather_kernel<<<N_ROIS, 256, 0, stream>>>(feat_cl, rois, out);
    } else {
        rroi_fallback_kernel<<<N_ROIS * NBIN, 64, 0, stream>>>(features, rois, out);
    }
}

// Round 3
// 179.129 us; speedup vs baseline: 1.3706x; 1.0082x over previous
//
#include <hip/hip_runtime.h>

// Problem constants (from reference setup_inputs)
constexpr int B_ = 2, C_ = 256, H_ = 200, W_ = 200;
constexpr int HW_ = H_ * W_;            // 40000
constexpr int N_ROIS = 512;
constexpr int OUT_H_ = 7, OUT_W_ = 7;
constexpr float SPATIAL_SCALE_ = 0.25f;
constexpr int NBIN = OUT_H_ * OUT_W_;   // 49
constexpr int OUT_PER_ROI = C_ * NBIN;  // 12544 floats

using f32x4 = __attribute__((ext_vector_type(4))) float;

// ---------------------------------------------------------------------------
// Kernel 0: rank-sort the 512 ROIs by (batch, y, x) so spatially adjacent
// ROIs get adjacent sorted indices -> L2 locality in the gather.
// One 512-thread block; rank[i] = #keys smaller (ties by index). perm[rank]=i.
// ---------------------------------------------------------------------------
__global__ __launch_bounds__(512) void roi_sort_kernel(
    const float* __restrict__ rois, int* __restrict__ perm) {
    __shared__ unsigned s_key[N_ROIS];
    const int i = threadIdx.x;
    const float* roi = rois + (size_t)i * 6;
    const int b  = (int)roi[0];
    const int ix = (int)(roi[1] * SPATIAL_SCALE_) & 255;
    const int iy = (int)(roi[2] * SPATIAL_SCALE_) & 255;
    const unsigned key = ((unsigned)b << 16) | ((unsigned)iy << 8) | (unsigned)ix;
    s_key[i] = key;
    __syncthreads();
    int rank = 0;
    for (int j = 0; j < N_ROIS; ++j) {
        const unsigned kj = s_key[j];
        rank += (kj < key) || (kj == key && j < i);
    }
    perm[rank] = i;
}

// ---------------------------------------------------------------------------
// Kernel 1: transpose (B, C, H, W) -> (B, H*W, C), float4 on both global sides.
// Tile: 64 pixels x 64 channels, block 256. Source loads nontemporal
// (read-once stream); dest stores normal (re-read by the gather).
// ---------------------------------------------------------------------------
__global__ __launch_bounds__(256) void transpose_cl_kernel(
    const float* __restrict__ in, float* __restrict__ out) {
    __shared__ float tile[64][68];
    const int b  = blockIdx.z;
    const int p0 = blockIdx.x * 64;   // pixel tile origin
    const int c0 = blockIdx.y * 64;   // channel tile origin
    const int tid = threadIdx.x;
    const int hi = tid >> 4;          // 0..15
    const int lo = tid & 15;          // 0..15

    const float* src = in  + (size_t)b * C_ * HW_;
    float*       dst = out + (size_t)b * HW_ * C_;

#pragma unroll
    for (int j = 0; j < 4; ++j) {
        const int cr = hi + j * 16;             // channel within tile
        const int pm = lo * 4;                  // pixel within tile
        const f32x4 v = __builtin_nontemporal_load(
            (const f32x4*)(src + (size_t)(c0 + cr) * HW_ + p0 + pm));
        tile[pm + 0][cr] = v.x;
        tile[pm + 1][cr] = v.y;
        tile[pm + 2][cr] = v.z;
        tile[pm + 3][cr] = v.w;
    }
    __syncthreads();
#pragma unroll
    for (int j = 0; j < 4; ++j) {
        const int pr = hi + j * 16;             // pixel within tile
        const int cm = lo * 4;                  // channel within tile
        const float4 r = *(const float4*)&tile[pr][cm];
        *(float4*)(dst + (size_t)(p0 + pr) * C_ + c0 + cm) = r;
    }
}

// ---------------------------------------------------------------------------
// Kernel 2: rotated ROI align, one 512-thread block (8 waves) per ROI.
// blockIdx -> sorted ROI via XCD-chunked swizzle: XCD k (bid&7) gets sorted
// chunk [k*64, (k+1)*64) -> spatially adjacent ROIs share that XCD's L2.
// Phase A: 196 threads compute sample offsets + premultiplied weights -> LDS.
// Phase B: wave w handles bins {w, w+8, ...}; lane owns 4 channels (float4);
//          4 corner loads are 1 KB coalesced reads from channels-last feat.
// Phase C: staged (C,49) result flushed float4-contiguous, nontemporal.
// ---------------------------------------------------------------------------
__global__ __launch_bounds__(512) void rroi_gather_kernel(
    const float* __restrict__ feat_cl,   // (B, H*W, C)
    const float* __restrict__ rois,
    const int* __restrict__ perm,        // may be nullptr
    float* __restrict__ out) {
    __shared__ float  s_out[OUT_PER_ROI];   // 50176 B, laid out [c][bin]
    __shared__ int    s_off[196];
    __shared__ float4 s_w[196];

    const int bid = blockIdx.x;
    const int sorted = (bid & 7) * (N_ROIS / 8) + (bid >> 3);
    const int n = perm ? perm[sorted] : bid;
    const int tid = threadIdx.x;

    const float* roi = rois + (size_t)n * 6;
    const int   b     = (int)roi[0];
    const float cx    = roi[1] * SPATIAL_SCALE_;
    const float cy    = roi[2] * SPATIAL_SCALE_;
    const float rw    = fmaxf(roi[3] * SPATIAL_SCALE_, 1.0f);
    const float rh    = fmaxf(roi[4] * SPATIAL_SCALE_, 1.0f);
    const float theta = roi[5];
    const float bin_h = rh / (float)OUT_H_;
    const float bin_w = rw / (float)OUT_W_;

    if (tid < 196) {
        const float cosT = cosf(theta);
        const float sinT = sinf(theta);
        const int bin = tid >> 2;
        const int s   = tid & 3;
        const int ph  = bin / OUT_W_;
        const int pw  = bin - ph * OUT_W_;
        const int s1  = s >> 1;
        const int s2  = s & 1;

        const float yy = -rh * 0.5f + ((float)ph + ((float)s1 + 0.5f) * 0.5f) * bin_h;
        const float xx = -rw * 0.5f + ((float)pw + ((float)s2 + 0.5f) * 0.5f) * bin_w;

        float x = xx * cosT + yy * sinT + cx;
        float y = yy * cosT - xx * sinT + cy;

        const bool valid = (y > -1.0f) && (y < (float)H_) &&
                           (x > -1.0f) && (x < (float)W_);

        y = fminf(fmaxf(y, 0.0f), (float)(H_ - 1));
        x = fminf(fmaxf(x, 0.0f), (float)(W_ - 1));
        int y0 = (int)floorf(y);  if (y0 > H_ - 2) y0 = H_ - 2;
        int x0 = (int)floorf(x);  if (x0 > W_ - 2) x0 = W_ - 2;

        const float ly = y - (float)y0;
        const float lx = x - (float)x0;
        const float hy = 1.0f - ly;
        const float hx = 1.0f - lx;
        const float m  = valid ? 0.25f : 0.0f;   // fold mean + validity

        s_w[tid]   = make_float4(hy * hx * m, hy * lx * m, ly * hx * m, ly * lx * m);
        s_off[tid] = (y0 * W_ + x0) * C_;
    }
    __syncthreads();

    const int wave = tid >> 6;           // 0..7
    const int lane = tid & 63;
    const float* base = feat_cl + (size_t)b * HW_ * C_ + 4 * lane;

    for (int bin = wave; bin < NBIN; bin += 8) {
        float4 acc = make_float4(0.f, 0.f, 0.f, 0.f);
#pragma unroll
        for (int s = 0; s < 4; ++s) {
            const int j = bin * 4 + s;
            const int off = s_off[j];
            const float4 w = s_w[j];
            const float* p = base + off;
            const float4 f00 = *(const float4*)p;
            const float4 f01 = *(const float4*)(p + C_);
            const float4 f10 = *(const float4*)(p + W_ * C_);
            const float4 f11 = *(const float4*)(p + W_ * C_ + C_);
            acc.x += w.x * f00.x + w.y * f01.x + w.z * f10.x + w.w * f11.x;
            acc.y += w.x * f00.y + w.y * f01.y + w.z * f10.y + w.w * f11.y;
            acc.z += w.x * f00.z + w.y * f01.z + w.z * f10.z + w.w * f11.z;
            acc.w += w.x * f00.w + w.y * f01.w + w.z * f10.w + w.w * f11.w;
        }
        const int c = 4 * lane;
        s_out[(c + 0) * NBIN + bin] = acc.x;
        s_out[(c + 1) * NBIN + bin] = acc.y;
        s_out[(c + 2) * NBIN + bin] = acc.z;
        s_out[(c + 3) * NBIN + bin] = acc.w;
    }
    __syncthreads();

    // Flush: 12544 floats = 3136 float4 = 6*512 + 64; nontemporal (no reuse)
    f32x4* o = (f32x4*)(out + (size_t)n * OUT_PER_ROI);
    const f32x4* l = (const f32x4*)s_out;
#pragma unroll
    for (int k = 0; k < 6; ++k) {
        __builtin_nontemporal_store(l[tid + 512 * k], o + tid + 512 * k);
    }
    if (tid < 64) __builtin_nontemporal_store(l[3072 + tid], o + 3072 + tid);
}

// ---------------------------------------------------------------------------
// Fallback (channels-first, scalar) — only if ws too small.
// ---------------------------------------------------------------------------
__global__ __launch_bounds__(64) void rroi_fallback_kernel(
    const float* __restrict__ feat,
    const float* __restrict__ rois,
    float* __restrict__ out) {
    const int blk = blockIdx.x;
    const int n   = blk / NBIN;
    const int bin = blk % NBIN;
    const int ph  = bin / OUT_W_;
    const int pw  = bin % OUT_W_;

    const float* roi = rois + (size_t)n * 6;
    const int   b     = (int)roi[0];
    const float cx    = roi[1] * SPATIAL_SCALE_;
    const float cy    = roi[2] * SPATIAL_SCALE_;
    const float rw    = fmaxf(roi[3] * SPATIAL_SCALE_, 1.0f);
    const float rh    = fmaxf(roi[4] * SPATIAL_SCALE_, 1.0f);
    const float theta = roi[5];
    const float bin_h = rh / (float)OUT_H_;
    const float bin_w = rw / (float)OUT_W_;
    const float cosT  = cosf(theta);
    const float sinT  = sinf(theta);
    const int t = threadIdx.x;
    float acc[4] = {0.f, 0.f, 0.f, 0.f};

#pragma unroll
    for (int s1 = 0; s1 < 2; ++s1) {
        const float yy = -rh * 0.5f + ((float)ph + ((float)s1 + 0.5f) * 0.5f) * bin_h;
#pragma unroll
        for (int s2 = 0; s2 < 2; ++s2) {
            const float xx = -rw * 0.5f + ((float)pw + ((float)s2 + 0.5f) * 0.5f) * bin_w;
            float x = xx * cosT + yy * sinT + cx;
            float y = yy * cosT - xx * sinT + cy;
            const bool valid = (y > -1.0f) && (y < (float)H_) &&
                               (x > -1.0f) && (x < (float)W_);
            if (!valid) continue;
            y = fminf(fmaxf(y, 0.0f), (float)(H_ - 1));
            x = fminf(fmaxf(x, 0.0f), (float)(W_ - 1));
            int y0 = (int)floorf(y);  if (y0 > H_ - 2) y0 = H_ - 2;
            int x0 = (int)floorf(x);  if (x0 > W_ - 2) x0 = W_ - 2;
            const float ly = y - (float)y0, lx = x - (float)x0;
            const float hy = 1.0f - ly, hx = 1.0f - lx;
            const float w00 = hy * hx, w01 = hy * lx, w10 = ly * hx, w11 = ly * lx;
            const int off0 = y0 * W_ + x0;
#pragma unroll
            for (int i = 0; i < 4; ++i) {
                const float* base = feat + ((size_t)b * C_ + 4 * t + i) * HW_;
                acc[i] += w00 * base[off0] + w01 * base[off0 + 1] +
                          w10 * base[off0 + W_] + w11 * base[off0 + W_ + 1];
            }
        }
    }
#pragma unroll
    for (int i = 0; i < 4; ++i) {
        out[((size_t)n * C_ + (4 * t + i)) * NBIN + bin] = acc[i] * 0.25f;
    }
}

extern "C" void kernel_launch(void* const* d_in, const int* in_sizes, int n_in,
                              void* d_out, int out_size, void* d_ws, size_t ws_size,
                              hipStream_t stream) {
    const float* features = (const float*)d_in[0];  // (B, C, H, W)
    const float* rois     = (const float*)d_in[1];  // (N, 6)
    float* out = (float*)d_out;                     // (N, C, 7, 7)

    const size_t feat_bytes = (size_t)B_ * C_ * HW_ * sizeof(float);  // 81,920,000
    const size_t perm_bytes = (size_t)N_ROIS * sizeof(int);

    if (ws_size >= feat_bytes + perm_bytes) {
        float* feat_cl = (float*)d_ws;
        int*   perm    = (int*)((char*)d_ws + feat_bytes);
        roi_sort_kernel<<<1, 512, 0, stream>>>(rois, perm);
        dim3 tg(HW_ / 64, C_ / 64, B_);
        transpose_cl_kernel<<<tg, 256, 0, stream>>>(features, feat_cl);
        rroi_gather_kernel<<<N_ROIS, 512, 0, stream>>>(feat_cl, rois, perm, out);
    } else if (ws_size >= feat_bytes) {
        float* feat_cl = (float*)d_ws;
        dim3 tg(HW_ / 64, C_ / 64, B_);
        transpose_cl_kernel<<<tg, 256, 0, stream>>>(features, feat_cl);
        rroi_gather_kernel<<<N_ROIS, 512, 0, stream>>>(feat_cl, rois, nullptr, out);
    } else {
        rroi_fallback_kernel<<<N_ROIS * NBIN, 64, 0, stream>>>(features, rois, out);
    }
}

// Round 4
// 158.825 us; speedup vs baseline: 1.5458x; 1.1278x over previous
//
#include <hip/hip_runtime.h>
#include <hip/hip_bf16.h>

// Problem constants (from reference setup_inputs)
constexpr int B_ = 2, C_ = 256, H_ = 200, W_ = 200;
constexpr int HW_ = H_ * W_;            // 40000
constexpr int N_ROIS = 512;
constexpr int OUT_H_ = 7, OUT_W_ = 7;
constexpr float SPATIAL_SCALE_ = 0.25f;
constexpr int NBIN = OUT_H_ * OUT_W_;   // 49
constexpr int OUT_PER_ROI = C_ * NBIN;  // 12544 floats

using f32x4 = __attribute__((ext_vector_type(4))) float;

// ---------------------------------------------------------------------------
// Kernel 0: rank-sort the 512 ROIs by (batch, y, x) for gather L2 locality.
// ---------------------------------------------------------------------------
__global__ __launch_bounds__(512) void roi_sort_kernel(
    const float* __restrict__ rois, int* __restrict__ perm) {
    __shared__ unsigned s_key[N_ROIS];
    const int i = threadIdx.x;
    const float* roi = rois + (size_t)i * 6;
    const int b  = (int)roi[0];
    const int ix = (int)(roi[1] * SPATIAL_SCALE_) & 255;
    const int iy = (int)(roi[2] * SPATIAL_SCALE_) & 255;
    const unsigned key = ((unsigned)b << 16) | ((unsigned)iy << 8) | (unsigned)ix;
    s_key[i] = key;
    __syncthreads();
    int rank = 0;
    for (int j = 0; j < N_ROIS; ++j) {
        const unsigned kj = s_key[j];
        rank += (kj < key) || (kj == key && j < i);
    }
    perm[rank] = i;
}

// ---------------------------------------------------------------------------
// Kernel 1: transpose+quantize (B, C, H, W) f32 -> (B, H*W, C) bf16.
// Tile 64 px x 64 ch, block 256, float4 global loads / ushort4 global stores.
// LDS tile[pixel][channel] pitch 65: scalar access both phases is
// conflict-free (bank = 4*lo + k + hi + 16j covers 64 distinct values).
// ---------------------------------------------------------------------------
__global__ __launch_bounds__(256) void transpose_bf_kernel(
    const float* __restrict__ in, __hip_bfloat16* __restrict__ out) {
    __shared__ float tile[64][65];
    const int b  = blockIdx.z;
    const int p0 = blockIdx.x * 64;   // pixel tile origin
    const int c0 = blockIdx.y * 64;   // channel tile origin
    const int tid = threadIdx.x;
    const int hi = tid >> 4;          // 0..15
    const int lo = tid & 15;          // 0..15

    const float* src = in + (size_t)b * C_ * HW_;
    __hip_bfloat16* dst = out + (size_t)b * HW_ * C_;

#pragma unroll
    for (int j = 0; j < 4; ++j) {
        const int cr = hi + j * 16;             // channel within tile
        const int pm = lo * 4;                  // pixel within tile
        const f32x4 v = __builtin_nontemporal_load(
            (const f32x4*)(src + (size_t)(c0 + cr) * HW_ + p0 + pm));
        tile[pm + 0][cr] = v.x;
        tile[pm + 1][cr] = v.y;
        tile[pm + 2][cr] = v.z;
        tile[pm + 3][cr] = v.w;
    }
    __syncthreads();
#pragma unroll
    for (int j = 0; j < 4; ++j) {
        const int pr = hi + j * 16;             // pixel within tile
        const int cm = lo * 4;                  // channel within tile
        ushort4 u;
        __hip_bfloat16 h0 = __float2bfloat16(tile[pr][cm + 0]);
        __hip_bfloat16 h1 = __float2bfloat16(tile[pr][cm + 1]);
        __hip_bfloat16 h2 = __float2bfloat16(tile[pr][cm + 2]);
        __hip_bfloat16 h3 = __float2bfloat16(tile[pr][cm + 3]);
        u.x = *(unsigned short*)&h0;
        u.y = *(unsigned short*)&h1;
        u.z = *(unsigned short*)&h2;
        u.w = *(unsigned short*)&h3;
        *(ushort4*)(dst + (size_t)(p0 + pr) * C_ + c0 + cm) = u;
    }
}

// ---------------------------------------------------------------------------
// Kernel 2: rotated ROI align from bf16 channels-last features.
// One 512-thread block (8 waves) per ROI; XCD-chunked swizzle over sorted perm.
// Lane owns channels {lane, lane+64, lane+128, lane+192} -> s_out writes are
// bank-conflict-free (stride 49*49... bank = 17*lane+bin, 17 invertible mod 32)
// and corner loads are 2 B/lane x 64 lanes = 128 B contiguous.
// ---------------------------------------------------------------------------
__global__ __launch_bounds__(512) void rroi_gather_kernel(
    const __hip_bfloat16* __restrict__ feat,   // (B, H*W, C) bf16
    const float* __restrict__ rois,
    const int* __restrict__ perm,              // may be nullptr
    float* __restrict__ out) {
    __shared__ float  s_out[OUT_PER_ROI];   // [c][bin], pitch 49
    __shared__ int    s_off[196];
    __shared__ float4 s_w[196];

    const int bid = blockIdx.x;
    const int sorted = (bid & 7) * (N_ROIS / 8) + (bid >> 3);
    const int n = perm ? perm[sorted] : bid;
    const int tid = threadIdx.x;

    const float* roi = rois + (size_t)n * 6;
    const int   b     = (int)roi[0];
    const float cx    = roi[1] * SPATIAL_SCALE_;
    const float cy    = roi[2] * SPATIAL_SCALE_;
    const float rw    = fmaxf(roi[3] * SPATIAL_SCALE_, 1.0f);
    const float rh    = fmaxf(roi[4] * SPATIAL_SCALE_, 1.0f);
    const float theta = roi[5];
    const float bin_h = rh / (float)OUT_H_;
    const float bin_w = rw / (float)OUT_W_;

    if (tid < 196) {
        const float cosT = cosf(theta);
        const float sinT = sinf(theta);
        const int bin = tid >> 2;
        const int s   = tid & 3;
        const int ph  = bin / OUT_W_;
        const int pw  = bin - ph * OUT_W_;
        const int s1  = s >> 1;
        const int s2  = s & 1;

        const float yy = -rh * 0.5f + ((float)ph + ((float)s1 + 0.5f) * 0.5f) * bin_h;
        const float xx = -rw * 0.5f + ((float)pw + ((float)s2 + 0.5f) * 0.5f) * bin_w;

        float x = xx * cosT + yy * sinT + cx;
        float y = yy * cosT - xx * sinT + cy;

        const bool valid = (y > -1.0f) && (y < (float)H_) &&
                           (x > -1.0f) && (x < (float)W_);

        y = fminf(fmaxf(y, 0.0f), (float)(H_ - 1));
        x = fminf(fmaxf(x, 0.0f), (float)(W_ - 1));
        int y0 = (int)floorf(y);  if (y0 > H_ - 2) y0 = H_ - 2;
        int x0 = (int)floorf(x);  if (x0 > W_ - 2) x0 = W_ - 2;

        const float ly = y - (float)y0;
        const float lx = x - (float)x0;
        const float hy = 1.0f - ly;
        const float hx = 1.0f - lx;
        const float m  = valid ? 0.25f : 0.0f;   // fold mean + validity

        s_w[tid]   = make_float4(hy * hx * m, hy * lx * m, ly * hx * m, ly * lx * m);
        s_off[tid] = (y0 * W_ + x0) * C_;
    }
    __syncthreads();

    const int wave = tid >> 6;           // 0..7
    const int lane = tid & 63;
    const __hip_bfloat16* base = feat + (size_t)b * HW_ * C_ + lane;

    for (int bin = wave; bin < NBIN; bin += 8) {
        float acc[4] = {0.f, 0.f, 0.f, 0.f};
#pragma unroll
        for (int s = 0; s < 4; ++s) {
            const int j = bin * 4 + s;
            const int off = s_off[j];
            const float4 w = s_w[j];
            const __hip_bfloat16* p = base + off;
#pragma unroll
            for (int m = 0; m < 4; ++m) {
                const __hip_bfloat16* q = p + 64 * m;
                const float f00 = __bfloat162float(q[0]);
                const float f01 = __bfloat162float(q[C_]);
                const float f10 = __bfloat162float(q[W_ * C_]);
                const float f11 = __bfloat162float(q[W_ * C_ + C_]);
                acc[m] += w.x * f00 + w.y * f01 + w.z * f10 + w.w * f11;
            }
        }
#pragma unroll
        for (int m = 0; m < 4; ++m) {
            s_out[(lane + 64 * m) * NBIN + bin] = acc[m];
        }
    }
    __syncthreads();

    // Flush: 12544 floats = 3136 float4 = 6*512 + 64; nontemporal (no reuse)
    f32x4* o = (f32x4*)(out + (size_t)n * OUT_PER_ROI);
    const f32x4* l = (const f32x4*)s_out;
#pragma unroll
    for (int k = 0; k < 6; ++k) {
        __builtin_nontemporal_store(l[tid + 512 * k], o + tid + 512 * k);
    }
    if (tid < 64) __builtin_nontemporal_store(l[3072 + tid], o + 3072 + tid);
}

// ---------------------------------------------------------------------------
// Fallback (channels-first f32, scalar) — only if ws too small.
// ---------------------------------------------------------------------------
__global__ __launch_bounds__(64) void rroi_fallback_kernel(
    const float* __restrict__ feat,
    const float* __restrict__ rois,
    float* __restrict__ out) {
    const int blk = blockIdx.x;
    const int n   = blk / NBIN;
    const int bin = blk % NBIN;
    const int ph  = bin / OUT_W_;
    const int pw  = bin % OUT_W_;

    const float* roi = rois + (size_t)n * 6;
    const int   b     = (int)roi[0];
    const float cx    = roi[1] * SPATIAL_SCALE_;
    const float cy    = roi[2] * SPATIAL_SCALE_;
    const float rw    = fmaxf(roi[3] * SPATIAL_SCALE_, 1.0f);
    const float rh    = fmaxf(roi[4] * SPATIAL_SCALE_, 1.0f);
    const float theta = roi[5];
    const float bin_h = rh / (float)OUT_H_;
    const float bin_w = rw / (float)OUT_W_;
    const float cosT  = cosf(theta);
    const float sinT  = sinf(theta);
    const int t = threadIdx.x;
    float acc[4] = {0.f, 0.f, 0.f, 0.f};

#pragma unroll
    for (int s1 = 0; s1 < 2; ++s1) {
        const float yy = -rh * 0.5f + ((float)ph + ((float)s1 + 0.5f) * 0.5f) * bin_h;
#pragma unroll
        for (int s2 = 0; s2 < 2; ++s2) {
            const float xx = -rw * 0.5f + ((float)pw + ((float)s2 + 0.5f) * 0.5f) * bin_w;
            float x = xx * cosT + yy * sinT + cx;
            float y = yy * cosT - xx * sinT + cy;
            const bool valid = (y > -1.0f) && (y < (float)H_) &&
                               (x > -1.0f) && (x < (float)W_);
            if (!valid) continue;
            y = fminf(fmaxf(y, 0.0f), (float)(H_ - 1));
            x = fminf(fmaxf(x, 0.0f), (float)(W_ - 1));
            int y0 = (int)floorf(y);  if (y0 > H_ - 2) y0 = H_ - 2;
            int x0 = (int)floorf(x);  if (x0 > W_ - 2) x0 = W_ - 2;
            const float ly = y - (float)y0, lx = x - (float)x0;
            const float hy = 1.0f - ly, hx = 1.0f - lx;
            const float w00 = hy * hx, w01 = hy * lx, w10 = ly * hx, w11 = ly * lx;
            const int off0 = y0 * W_ + x0;
#pragma unroll
            for (int i = 0; i < 4; ++i) {
                const float* basep = feat + ((size_t)b * C_ + 4 * t + i) * HW_;
                acc[i] += w00 * basep[off0] + w01 * basep[off0 + 1] +
                          w10 * basep[off0 + W_] + w11 * basep[off0 + W_ + 1];
            }
        }
    }
#pragma unroll
    for (int i = 0; i < 4; ++i) {
        out[((size_t)n * C_ + (4 * t + i)) * NBIN + bin] = acc[i] * 0.25f;
    }
}

extern "C" void kernel_launch(void* const* d_in, const int* in_sizes, int n_in,
                              void* d_out, int out_size, void* d_ws, size_t ws_size,
                              hipStream_t stream) {
    const float* features = (const float*)d_in[0];  // (B, C, H, W)
    const float* rois     = (const float*)d_in[1];  // (N, 6)
    float* out = (float*)d_out;                     // (N, C, 7, 7)

    const size_t feat_bytes = (size_t)B_ * C_ * HW_ * sizeof(__hip_bfloat16); // 40.96 MB
    const size_t perm_bytes = (size_t)N_ROIS * sizeof(int);

    if (ws_size >= feat_bytes + perm_bytes) {
        __hip_bfloat16* feat_bf = (__hip_bfloat16*)d_ws;
        int* perm = (int*)((char*)d_ws + ((feat_bytes + 255) & ~(size_t)255));
        roi_sort_kernel<<<1, 512, 0, stream>>>(rois, perm);
        dim3 tg(HW_ / 64, C_ / 64, B_);
        transpose_bf_kernel<<<tg, 256, 0, stream>>>(features, feat_bf);
        rroi_gather_kernel<<<N_ROIS, 512, 0, stream>>>(feat_bf, rois, perm, out);
    } else if (ws_size >= feat_bytes) {
        __hip_bfloat16* feat_bf = (__hip_bfloat16*)d_ws;
        dim3 tg(HW_ / 64, C_ / 64, B_);
        transpose_bf_kernel<<<tg, 256, 0, stream>>>(features, feat_bf);
        rroi_gather_kernel<<<N_ROIS, 512, 0, stream>>>(feat_bf, rois, nullptr, out);
    } else {
        rroi_fallback_kernel<<<N_ROIS * NBIN, 64, 0, stream>>>(features, rois, out);
    }
}

// Round 6
// 156.699 us; speedup vs baseline: 1.5668x; 1.0136x over previous
//
#include <hip/hip_runtime.h>
#include <hip/hip_bf16.h>

// Problem constants (from reference setup_inputs)
constexpr int B_ = 2, C_ = 256, H_ = 200, W_ = 200;
constexpr int HW_ = H_ * W_;            // 40000
constexpr int N_ROIS = 512;
constexpr int OUT_H_ = 7, OUT_W_ = 7;
constexpr float SPATIAL_SCALE_ = 0.25f;
constexpr int NBIN = OUT_H_ * OUT_W_;   // 49
constexpr int OUT_PER_ROI = C_ * NBIN;  // 12544 floats
constexpr int HALF_C = C_ / 2;          // 128
constexpr int HALF_OUT = HALF_C * NBIN; // 6272 floats

using f32x4 = __attribute__((ext_vector_type(4))) float;

__device__ __forceinline__ float bf_lo(unsigned u) {
    const unsigned v = u << 16;
    return __builtin_bit_cast(float, v);
}
__device__ __forceinline__ float bf_hi(unsigned u) {
    const unsigned v = u & 0xffff0000u;
    return __builtin_bit_cast(float, v);
}

// ---------------------------------------------------------------------------
// Kernel 0: rank-sort the 512 ROIs by (batch, y, x) for gather L2 locality.
// ---------------------------------------------------------------------------
__global__ __launch_bounds__(512) void roi_sort_kernel(
    const float* __restrict__ rois, int* __restrict__ perm) {
    __shared__ unsigned s_key[N_ROIS];
    const int i = threadIdx.x;
    const float* roi = rois + (size_t)i * 6;
    const int b  = (int)roi[0];
    const int ix = (int)(roi[1] * SPATIAL_SCALE_) & 255;
    const int iy = (int)(roi[2] * SPATIAL_SCALE_) & 255;
    const unsigned key = ((unsigned)b << 16) | ((unsigned)iy << 8) | (unsigned)ix;
    s_key[i] = key;
    __syncthreads();
    int rank = 0;
    for (int j = 0; j < N_ROIS; ++j) {
        const unsigned kj = s_key[j];
        rank += (kj < key) || (kj == key && j < i);
    }
    perm[rank] = i;
}

// ---------------------------------------------------------------------------
// Kernel 1: transpose+quantize (B, C, H, W) f32 -> (B, H*W, C) bf16.
// Tile 64 px x 64 ch, block 256, float4 global loads / ushort4 global stores.
// LDS pitch 65 -> scalar access conflict-free both phases.
// ---------------------------------------------------------------------------
__global__ __launch_bounds__(256) void transpose_bf_kernel(
    const float* __restrict__ in, __hip_bfloat16* __restrict__ out) {
    __shared__ float tile[64][65];
    const int b  = blockIdx.z;
    const int p0 = blockIdx.x * 64;   // pixel tile origin
    const int c0 = blockIdx.y * 64;   // channel tile origin
    const int tid = threadIdx.x;
    const int hi = tid >> 4;          // 0..15
    const int lo = tid & 15;          // 0..15

    const float* src = in + (size_t)b * C_ * HW_;
    __hip_bfloat16* dst = out + (size_t)b * HW_ * C_;

#pragma unroll
    for (int j = 0; j < 4; ++j) {
        const int cr = hi + j * 16;             // channel within tile
        const int pm = lo * 4;                  // pixel within tile
        const f32x4 v = __builtin_nontemporal_load(
            (const f32x4*)(src + (size_t)(c0 + cr) * HW_ + p0 + pm));
        tile[pm + 0][cr] = v.x;
        tile[pm + 1][cr] = v.y;
        tile[pm + 2][cr] = v.z;
        tile[pm + 3][cr] = v.w;
    }
    __syncthreads();
#pragma unroll
    for (int j = 0; j < 4; ++j) {
        const int pr = hi + j * 16;             // pixel within tile
        const int cm = lo * 4;                  // channel within tile
        ushort4 u;
        __hip_bfloat16 h0 = __float2bfloat16(tile[pr][cm + 0]);
        __hip_bfloat16 h1 = __float2bfloat16(tile[pr][cm + 1]);
        __hip_bfloat16 h2 = __float2bfloat16(tile[pr][cm + 2]);
        __hip_bfloat16 h3 = __float2bfloat16(tile[pr][cm + 3]);
        u.x = *(unsigned short*)&h0;
        u.y = *(unsigned short*)&h1;
        u.z = *(unsigned short*)&h2;
        u.w = *(unsigned short*)&h3;
        *(ushort4*)(dst + (size_t)(p0 + pr) * C_ + c0 + cm) = u;
    }
}

// ---------------------------------------------------------------------------
// Kernel 2: rotated ROI align from bf16 channels-last features.
// Grid 1024 = (roi, channel-half). 512 threads, ~29 KB LDS, forced <=64 VGPR
// -> 4 blocks/CU = 32 waves/CU (100% occupancy; grid is exactly 4/CU).
// slot swizzle: XCD k gets sorted slots [k*128,(k+1)*128) -> both halves of
// an ROI and 64 spatially-adjacent ROIs share one XCD's L2 (~4 MB footprint).
// Lane owns 2 adjacent channels (one uint = 2 bf16 per corner load; 256 B/wave
// coalesced). s_out[c_local*49+bin] writes are 4-way conflicted (1.58x, minor).
// ---------------------------------------------------------------------------
__global__ __launch_bounds__(512, 8) void rroi_gather_kernel(
    const __hip_bfloat16* __restrict__ feat,   // (B, H*W, C) bf16
    const float* __restrict__ rois,
    const int* __restrict__ perm,              // may be nullptr
    float* __restrict__ out) {
    __shared__ float  s_out[HALF_OUT];      // [c_local][bin], pitch 49
    __shared__ int    s_off[196];           // corner offset in UINT units
    __shared__ float4 s_w[196];

    const int bid  = blockIdx.x;
    const int slot = (bid & 7) * 128 + (bid >> 3);   // XCD-chunked
    const int s_i  = slot >> 1;                      // sorted roi index
    const int h    = slot & 1;                       // channel half
    const int n    = perm ? perm[s_i] : s_i;
    const int tid  = threadIdx.x;

    const float* roi = rois + (size_t)n * 6;
    const int   b     = (int)roi[0];
    const float cx    = roi[1] * SPATIAL_SCALE_;
    const float cy    = roi[2] * SPATIAL_SCALE_;
    const float rw    = fmaxf(roi[3] * SPATIAL_SCALE_, 1.0f);
    const float rh    = fmaxf(roi[4] * SPATIAL_SCALE_, 1.0f);
    const float theta = roi[5];
    const float bin_h = rh / (float)OUT_H_;
    const float bin_w = rw / (float)OUT_W_;

    if (tid < 196) {
        const float cosT = cosf(theta);
        const float sinT = sinf(theta);
        const int bin = tid >> 2;
        const int s   = tid & 3;
        const int ph  = bin / OUT_W_;
        const int pw  = bin - ph * OUT_W_;
        const int s1  = s >> 1;
        const int s2  = s & 1;

        const float yy = -rh * 0.5f + ((float)ph + ((float)s1 + 0.5f) * 0.5f) * bin_h;
        const float xx = -rw * 0.5f + ((float)pw + ((float)s2 + 0.5f) * 0.5f) * bin_w;

        float x = xx * cosT + yy * sinT + cx;
        float y = yy * cosT - xx * sinT + cy;

        const bool valid = (y > -1.0f) && (y < (float)H_) &&
                           (x > -1.0f) && (x < (float)W_);

        y = fminf(fmaxf(y, 0.0f), (float)(H_ - 1));
        x = fminf(fmaxf(x, 0.0f), (float)(W_ - 1));
        int y0 = (int)floorf(y);  if (y0 > H_ - 2) y0 = H_ - 2;
        int x0 = (int)floorf(x);  if (x0 > W_ - 2) x0 = W_ - 2;

        const float ly = y - (float)y0;
        const float lx = x - (float)x0;
        const float hy = 1.0f - ly;
        const float hx = 1.0f - lx;
        const float m  = valid ? 0.25f : 0.0f;   // fold mean + validity

        s_w[tid]   = make_float4(hy * hx * m, hy * lx * m, ly * hx * m, ly * lx * m);
        s_off[tid] = (y0 * W_ + x0) * (C_ / 2);  // uint units (2 bf16 / uint)
    }
    __syncthreads();

    const int wave = tid >> 6;           // 0..7
    const int lane = tid & 63;
    // uint view: channel pair index = h*64 + lane
    const unsigned* base =
        (const unsigned*)(feat + (size_t)b * HW_ * C_) + h * 64 + lane;

    for (int bin = wave; bin < NBIN; bin += 8) {
        float acc0 = 0.f, acc1 = 0.f;
#pragma unroll
        for (int s = 0; s < 4; ++s) {
            const int j = bin * 4 + s;
            const int off = s_off[j];
            const float4 w = s_w[j];
            const unsigned* p = base + off;
            const unsigned u00 = p[0];
            const unsigned u01 = p[C_ / 2];
            const unsigned u10 = p[W_ * (C_ / 2)];
            const unsigned u11 = p[W_ * (C_ / 2) + C_ / 2];
            acc0 += w.x * bf_lo(u00) + w.y * bf_lo(u01) +
                    w.z * bf_lo(u10) + w.w * bf_lo(u11);
            acc1 += w.x * bf_hi(u00) + w.y * bf_hi(u01) +
                    w.z * bf_hi(u10) + w.w * bf_hi(u11);
        }
        const int c = 2 * lane;
        s_out[(c + 0) * NBIN + bin] = acc0;
        s_out[(c + 1) * NBIN + bin] = acc1;
    }
    __syncthreads();

    // Flush half-slice: 6272 floats = 1568 float4 = 3*512 + 32; nontemporal.
    f32x4* o = (f32x4*)(out + (size_t)n * OUT_PER_ROI + h * HALF_OUT);
    const f32x4* l = (const f32x4*)s_out;
#pragma unroll
    for (int k = 0; k < 3; ++k) {
        __builtin_nontemporal_store(l[tid + 512 * k], o + tid + 512 * k);
    }
    if (tid < 32) __builtin_nontemporal_store(l[1536 + tid], o + 1536 + tid);
}

// ---------------------------------------------------------------------------
// Fallback (channels-first f32, scalar) — only if ws too small.
// ---------------------------------------------------------------------------
__global__ __launch_bounds__(64) void rroi_fallback_kernel(
    const float* __restrict__ feat,
    const float* __restrict__ rois,
    float* __restrict__ out) {
    const int blk = blockIdx.x;
    const int n   = blk / NBIN;
    const int bin = blk % NBIN;
    const int ph  = bin / OUT_W_;
    const int pw  = bin % OUT_W_;

    const float* roi = rois + (size_t)n * 6;
    const int   b     = (int)roi[0];
    const float cx    = roi[1] * SPATIAL_SCALE_;
    const float cy    = roi[2] * SPATIAL_SCALE_;
    const float rw    = fmaxf(roi[3] * SPATIAL_SCALE_, 1.0f);
    const float rh    = fmaxf(roi[4] * SPATIAL_SCALE_, 1.0f);
    const float theta = roi[5];
    const float bin_h = rh / (float)OUT_H_;
    const float bin_w = rw / (float)OUT_W_;
    const float cosT  = cosf(theta);
    const float sinT  = sinf(theta);
    const int t = threadIdx.x;
    float acc[4] = {0.f, 0.f, 0.f, 0.f};

#pragma unroll
    for (int s1 = 0; s1 < 2; ++s1) {
        const float yy = -rh * 0.5f + ((float)ph + ((float)s1 + 0.5f) * 0.5f) * bin_h;
#pragma unroll
        for (int s2 = 0; s2 < 2; ++s2) {
            const float xx = -rw * 0.5f + ((float)pw + ((float)s2 + 0.5f) * 0.5f) * bin_w;
            float x = xx * cosT + yy * sinT + cx;
            float y = yy * cosT - xx * sinT + cy;
            const bool valid = (y > -1.0f) && (y < (float)H_) &&
                               (x > -1.0f) && (x < (float)W_);
            if (!valid) continue;
            y = fminf(fmaxf(y, 0.0f), (float)(H_ - 1));
            x = fminf(fmaxf(x, 0.0f), (float)(W_ - 1));
            int y0 = (int)floorf(y);  if (y0 > H_ - 2) y0 = H_ - 2;
            int x0 = (int)floorf(x);  if (x0 > W_ - 2) x0 = W_ - 2;
            const float ly = y - (float)y0, lx = x - (float)x0;
            const float hy = 1.0f - ly, hx = 1.0f - lx;
            const float w00 = hy * hx, w01 = hy * lx, w10 = ly * hx, w11 = ly * lx;
            const int off0 = y0 * W_ + x0;
#pragma unroll
            for (int i = 0; i < 4; ++i) {
                const float* basep = feat + ((size_t)b * C_ + 4 * t + i) * HW_;
                acc[i] += w00 * basep[off0] + w01 * basep[off0 + 1] +
                          w10 * basep[off0 + W_] + w11 * basep[off0 + W_ + 1];
            }
        }
    }
#pragma unroll
    for (int i = 0; i < 4; ++i) {
        out[((size_t)n * C_ + (4 * t + i)) * NBIN + bin] = acc[i] * 0.25f;
    }
}

extern "C" void kernel_launch(void* const* d_in, const int* in_sizes, int n_in,
                              void* d_out, int out_size, void* d_ws, size_t ws_size,
                              hipStream_t stream) {
    const float* features = (const float*)d_in[0];  // (B, C, H, W)
    const float* rois     = (const float*)d_in[1];  // (N, 6)
    float* out = (float*)d_out;                     // (N, C, 7, 7)

    const size_t feat_bytes = (size_t)B_ * C_ * HW_ * sizeof(__hip_bfloat16); // 40.96 MB
    const size_t perm_bytes = (size_t)N_ROIS * sizeof(int);

    if (ws_size >= feat_bytes + 256 + perm_bytes) {
        __hip_bfloat16* feat_bf = (__hip_bfloat16*)d_ws;
        int* perm = (int*)((char*)d_ws + ((feat_bytes + 255) & ~(size_t)255));
        roi_sort_kernel<<<1, 512, 0, stream>>>(rois, perm);
        dim3 tg(HW_ / 64, C_ / 64, B_);
        transpose_bf_kernel<<<tg, 256, 0, stream>>>(features, feat_bf);
        rroi_gather_kernel<<<N_ROIS * 2, 512, 0, stream>>>(feat_bf, rois, perm, out);
    } else if (ws_size >= feat_bytes) {
        __hip_bfloat16* feat_bf = (__hip_bfloat16*)d_ws;
        dim3 tg(HW_ / 64, C_ / 64, B_);
        transpose_bf_kernel<<<tg, 256, 0, stream>>>(features, feat_bf);
        rroi_gather_kernel<<<N_ROIS * 2, 512, 0, stream>>>(feat_bf, rois, nullptr, out);
    } else {
        rroi_fallback_kernel<<<N_ROIS * NBIN, 64, 0, stream>>>(features, rois, out);
    }
}

// Round 7
// 154.644 us; speedup vs baseline: 1.5876x; 1.0133x over previous
//
#include <hip/hip_runtime.h>
#include <hip/hip_bf16.h>

// Problem constants (from reference setup_inputs)
constexpr int B_ = 2, C_ = 256, H_ = 200, W_ = 200;
constexpr int HW_ = H_ * W_;            // 40000
constexpr int N_ROIS = 512;
constexpr int OUT_H_ = 7, OUT_W_ = 7;
constexpr float SPATIAL_SCALE_ = 0.25f;
constexpr int NBIN = OUT_H_ * OUT_W_;   // 49
constexpr int OUT_PER_ROI = C_ * NBIN;  // 12544 floats
constexpr int PIX = C_ / 8;             // uint4 per pixel row in ch-last = 32

using f32x4 = __attribute__((ext_vector_type(4))) float;

__device__ __forceinline__ float bf_lo(unsigned u) {
    const unsigned v = u << 16;
    return __builtin_bit_cast(float, v);
}
__device__ __forceinline__ float bf_hi(unsigned u) {
    const unsigned v = u & 0xffff0000u;
    return __builtin_bit_cast(float, v);
}
__device__ __forceinline__ unsigned bf_pack(float a, float b) {
    __hip_bfloat16 ha = __float2bfloat16(a);
    __hip_bfloat16 hb = __float2bfloat16(b);
    return (unsigned)*(unsigned short*)&ha |
           ((unsigned)*(unsigned short*)&hb << 16);
}

// ---------------------------------------------------------------------------
// Kernel 0: rank-sort the 512 ROIs by (batch, y, x) for gather L2 locality.
// ---------------------------------------------------------------------------
__global__ __launch_bounds__(512) void roi_sort_kernel(
    const float* __restrict__ rois, int* __restrict__ perm) {
    __shared__ unsigned s_key[N_ROIS];
    const int i = threadIdx.x;
    const float* roi = rois + (size_t)i * 6;
    const int b  = (int)roi[0];
    const int ix = (int)(roi[1] * SPATIAL_SCALE_) & 255;
    const int iy = (int)(roi[2] * SPATIAL_SCALE_) & 255;
    const unsigned key = ((unsigned)b << 16) | ((unsigned)iy << 8) | (unsigned)ix;
    s_key[i] = key;
    __syncthreads();
    int rank = 0;
    for (int j = 0; j < N_ROIS; ++j) {
        const unsigned kj = s_key[j];
        rank += (kj < key) || (kj == key && j < i);
    }
    perm[rank] = i;
}

// ---------------------------------------------------------------------------
// Kernel 1: transpose+quantize (B, C, H, W) f32 -> (B, H*W, C) bf16.
// Tile 64 px x 64 ch, block 256. Loads: float4 nontemporal (read-once).
// Stores: uint4 = 8 bf16 channels per instruction.
// LDS pitch 65: load-phase scalar writes conflict-free; store-phase reads
// tile[pr][8*(t&7)+i] -> bank = pr + 8*(t&7) + i mod 32 -> 2-way = free.
// ---------------------------------------------------------------------------
__global__ __launch_bounds__(256) void transpose_bf_kernel(
    const float* __restrict__ in, __hip_bfloat16* __restrict__ out) {
    __shared__ float tile[64][65];
    const int b  = blockIdx.z;
    const int p0 = blockIdx.x * 64;   // pixel tile origin
    const int c0 = blockIdx.y * 64;   // channel tile origin
    const int tid = threadIdx.x;
    const int hi = tid >> 4;          // 0..15
    const int lo = tid & 15;          // 0..15

    const float* src = in + (size_t)b * C_ * HW_;
    __hip_bfloat16* dst = out + (size_t)b * HW_ * C_;

#pragma unroll
    for (int j = 0; j < 4; ++j) {
        const int cr = hi + j * 16;             // channel within tile
        const int pm = lo * 4;                  // pixel within tile
        const f32x4 v = __builtin_nontemporal_load(
            (const f32x4*)(src + (size_t)(c0 + cr) * HW_ + p0 + pm));
        tile[pm + 0][cr] = v.x;
        tile[pm + 1][cr] = v.y;
        tile[pm + 2][cr] = v.z;
        tile[pm + 3][cr] = v.w;
    }
    __syncthreads();
#pragma unroll
    for (int j = 0; j < 2; ++j) {
        const int pr = (tid >> 3) + j * 32;     // pixel within tile 0..63
        const int cm = 8 * (tid & 7);           // channel within tile
        uint4 u;
        u.x = bf_pack(tile[pr][cm + 0], tile[pr][cm + 1]);
        u.y = bf_pack(tile[pr][cm + 2], tile[pr][cm + 3]);
        u.z = bf_pack(tile[pr][cm + 4], tile[pr][cm + 5]);
        u.w = bf_pack(tile[pr][cm + 6], tile[pr][cm + 7]);
        *(uint4*)(dst + (size_t)(p0 + pr) * C_ + c0 + cm) = u;
    }
}

// ---------------------------------------------------------------------------
// Kernel 2: rotated ROI align from bf16 channels-last features.
// One 512-thread block per ROI (grid 512 = exactly 2 blocks/CU).
// Half-wave hw = tid>>5 owns bins {hw, hw+16, ...}; lane cl = tid&31 owns
// 8 adjacent channels -> each corner is ONE uint4 load (32 lanes x 16 B =
// 512 B coalesced). Per-lane loads ~52 (4x fewer VMEM instrs than r6).
// XCD-chunked swizzle over sorted perm keeps each XCD on 64 adjacent ROIs.
// ---------------------------------------------------------------------------
__global__ __launch_bounds__(512, 4) void rroi_gather_kernel(
    const __hip_bfloat16* __restrict__ feat,   // (B, H*W, C) bf16
    const float* __restrict__ rois,
    const int* __restrict__ perm,              // may be nullptr
    float* __restrict__ out) {
    __shared__ float  s_out[OUT_PER_ROI];   // 50176 B, [c][bin] pitch 49
    __shared__ int    s_pix[196];           // pixel index y0*W + x0
    __shared__ float4 s_w[196];

    const int bid  = blockIdx.x;
    const int slot = (bid & 7) * 64 + (bid >> 3);    // XCD-chunked
    const int n    = perm ? perm[slot] : slot;
    const int tid  = threadIdx.x;

    const float* roi = rois + (size_t)n * 6;
    const int   b     = (int)roi[0];
    const float cx    = roi[1] * SPATIAL_SCALE_;
    const float cy    = roi[2] * SPATIAL_SCALE_;
    const float rw    = fmaxf(roi[3] * SPATIAL_SCALE_, 1.0f);
    const float rh    = fmaxf(roi[4] * SPATIAL_SCALE_, 1.0f);
    const float theta = roi[5];
    const float bin_h = rh / (float)OUT_H_;
    const float bin_w = rw / (float)OUT_W_;

    if (tid < 196) {
        const float cosT = cosf(theta);
        const float sinT = sinf(theta);
        const int bin = tid >> 2;
        const int s   = tid & 3;
        const int ph  = bin / OUT_W_;
        const int pw  = bin - ph * OUT_W_;
        const int s1  = s >> 1;
        const int s2  = s & 1;

        const float yy = -rh * 0.5f + ((float)ph + ((float)s1 + 0.5f) * 0.5f) * bin_h;
        const float xx = -rw * 0.5f + ((float)pw + ((float)s2 + 0.5f) * 0.5f) * bin_w;

        float x = xx * cosT + yy * sinT + cx;
        float y = yy * cosT - xx * sinT + cy;

        const bool valid = (y > -1.0f) && (y < (float)H_) &&
                           (x > -1.0f) && (x < (float)W_);

        y = fminf(fmaxf(y, 0.0f), (float)(H_ - 1));
        x = fminf(fmaxf(x, 0.0f), (float)(W_ - 1));
        int y0 = (int)floorf(y);  if (y0 > H_ - 2) y0 = H_ - 2;
        int x0 = (int)floorf(x);  if (x0 > W_ - 2) x0 = W_ - 2;

        const float ly = y - (float)y0;
        const float lx = x - (float)x0;
        const float hy = 1.0f - ly;
        const float hx = 1.0f - lx;
        const float m  = valid ? 0.25f : 0.0f;   // fold mean + validity

        s_w[tid]   = make_float4(hy * hx * m, hy * lx * m, ly * hx * m, ly * lx * m);
        s_pix[tid] = y0 * W_ + x0;
    }
    __syncthreads();

    const int hw = tid >> 5;             // half-wave id 0..15
    const int cl = tid & 31;             // channel-octet id
    const uint4* base = (const uint4*)(feat + (size_t)b * HW_ * C_) + cl;

    for (int bin = hw; bin < NBIN; bin += 16) {
        float acc[8] = {0.f, 0.f, 0.f, 0.f, 0.f, 0.f, 0.f, 0.f};
#pragma unroll
        for (int s = 0; s < 4; ++s) {
            const int j = bin * 4 + s;
            const float4 w = s_w[j];
            const uint4* p = base + s_pix[j] * PIX;
            const uint4 u00 = p[0];
            const uint4 u01 = p[PIX];
            const uint4 u10 = p[W_ * PIX];
            const uint4 u11 = p[W_ * PIX + PIX];

            acc[0] += w.x * bf_lo(u00.x) + w.y * bf_lo(u01.x) +
                      w.z * bf_lo(u10.x) + w.w * bf_lo(u11.x);
            acc[1] += w.x * bf_hi(u00.x) + w.y * bf_hi(u01.x) +
                      w.z * bf_hi(u10.x) + w.w * bf_hi(u11.x);
            acc[2] += w.x * bf_lo(u00.y) + w.y * bf_lo(u01.y) +
                      w.z * bf_lo(u10.y) + w.w * bf_lo(u11.y);
            acc[3] += w.x * bf_hi(u00.y) + w.y * bf_hi(u01.y) +
                      w.z * bf_hi(u10.y) + w.w * bf_hi(u11.y);
            acc[4] += w.x * bf_lo(u00.z) + w.y * bf_lo(u01.z) +
                      w.z * bf_lo(u10.z) + w.w * bf_lo(u11.z);
            acc[5] += w.x * bf_hi(u00.z) + w.y * bf_hi(u01.z) +
                      w.z * bf_hi(u10.z) + w.w * bf_hi(u11.z);
            acc[6] += w.x * bf_lo(u00.w) + w.y * bf_lo(u01.w) +
                      w.z * bf_lo(u10.w) + w.w * bf_lo(u11.w);
            acc[7] += w.x * bf_hi(u00.w) + w.y * bf_hi(u01.w) +
                      w.z * bf_hi(u10.w) + w.w * bf_hi(u11.w);
        }
        const int c = 8 * cl;
#pragma unroll
        for (int i = 0; i < 8; ++i) {
            s_out[(c + i) * NBIN + bin] = acc[i];
        }
    }
    __syncthreads();

    // Flush: 12544 floats = 3136 float4 = 6*512 + 64; nontemporal (no reuse).
    f32x4* o = (f32x4*)(out + (size_t)n * OUT_PER_ROI);
    const f32x4* l = (const f32x4*)s_out;
#pragma unroll
    for (int k = 0; k < 6; ++k) {
        __builtin_nontemporal_store(l[tid + 512 * k], o + tid + 512 * k);
    }
    if (tid < 64) __builtin_nontemporal_store(l[3072 + tid], o + 3072 + tid);
}

// ---------------------------------------------------------------------------
// Fallback (channels-first f32, scalar) — only if ws too small.
// ---------------------------------------------------------------------------
__global__ __launch_bounds__(64) void rroi_fallback_kernel(
    const float* __restrict__ feat,
    const float* __restrict__ rois,
    float* __restrict__ out) {
    const int blk = blockIdx.x;
    const int n   = blk / NBIN;
    const int bin = blk % NBIN;
    const int ph  = bin / OUT_W_;
    const int pw  = bin % OUT_W_;

    const float* roi = rois + (size_t)n * 6;
    const int   b     = (int)roi[0];
    const float cx    = roi[1] * SPATIAL_SCALE_;
    const float cy    = roi[2] * SPATIAL_SCALE_;
    const float rw    = fmaxf(roi[3] * SPATIAL_SCALE_, 1.0f);
    const float rh    = fmaxf(roi[4] * SPATIAL_SCALE_, 1.0f);
    const float theta = roi[5];
    const float bin_h = rh / (float)OUT_H_;
    const float bin_w = rw / (float)OUT_W_;
    const float cosT  = cosf(theta);
    const float sinT  = sinf(theta);
    const int t = threadIdx.x;
    float acc[4] = {0.f, 0.f, 0.f, 0.f};

#pragma unroll
    for (int s1 = 0; s1 < 2; ++s1) {
        const float yy = -rh * 0.5f + ((float)ph + ((float)s1 + 0.5f) * 0.5f) * bin_h;
#pragma unroll
        for (int s2 = 0; s2 < 2; ++s2) {
            const float xx = -rw * 0.5f + ((float)pw + ((float)s2 + 0.5f) * 0.5f) * bin_w;
            float x = xx * cosT + yy * sinT + cx;
            float y = yy * cosT - xx * sinT + cy;
            const bool valid = (y > -1.0f) && (y < (float)H_) &&
                               (x > -1.0f) && (x < (float)W_);
            if (!valid) continue;
            y = fminf(fmaxf(y, 0.0f), (float)(H_ - 1));
            x = fminf(fmaxf(x, 0.0f), (float)(W_ - 1));
            int y0 = (int)floorf(y);  if (y0 > H_ - 2) y0 = H_ - 2;
            int x0 = (int)floorf(x);  if (x0 > W_ - 2) x0 = W_ - 2;
            const float ly = y - (float)y0, lx = x - (float)x0;
            const float hy = 1.0f - ly, hx = 1.0f - lx;
            const float w00 = hy * hx, w01 = hy * lx, w10 = ly * hx, w11 = ly * lx;
            const int off0 = y0 * W_ + x0;
#pragma unroll
            for (int i = 0; i < 4; ++i) {
                const float* basep = feat + ((size_t)b * C_ + 4 * t + i) * HW_;
                acc[i] += w00 * basep[off0] + w01 * basep[off0 + 1] +
                          w10 * basep[off0 + W_] + w11 * basep[off0 + W_ + 1];
            }
        }
    }
#pragma unroll
    for (int i = 0; i < 4; ++i) {
        out[((size_t)n * C_ + (4 * t + i)) * NBIN + bin] = acc[i] * 0.25f;
    }
}

extern "C" void kernel_launch(void* const* d_in, const int* in_sizes, int n_in,
                              void* d_out, int out_size, void* d_ws, size_t ws_size,
                              hipStream_t stream) {
    const float* features = (const float*)d_in[0];  // (B, C, H, W)
    const float* rois     = (const float*)d_in[1];  // (N, 6)
    float* out = (float*)d_out;                     // (N, C, 7, 7)

    const size_t feat_bytes = (size_t)B_ * C_ * HW_ * sizeof(__hip_bfloat16); // 40.96 MB
    const size_t perm_bytes = (size_t)N_ROIS * sizeof(int);

    if (ws_size >= feat_bytes + 256 + perm_bytes) {
        __hip_bfloat16* feat_bf = (__hip_bfloat16*)d_ws;
        int* perm = (int*)((char*)d_ws + ((feat_bytes + 255) & ~(size_t)255));
        roi_sort_kernel<<<1, 512, 0, stream>>>(rois, perm);
        dim3 tg(HW_ / 64, C_ / 64, B_);
        transpose_bf_kernel<<<tg, 256, 0, stream>>>(features, feat_bf);
        rroi_gather_kernel<<<N_ROIS, 512, 0, stream>>>(feat_bf, rois, perm, out);
    } else if (ws_size >= feat_bytes) {
        __hip_bfloat16* feat_bf = (__hip_bfloat16*)d_ws;
        dim3 tg(HW_ / 64, C_ / 64, B_);
        transpose_bf_kernel<<<tg, 256, 0, stream>>>(features, feat_bf);
        rroi_gather_kernel<<<N_ROIS, 512, 0, stream>>>(feat_bf, rois, nullptr, out);
    } else {
        rroi_fallback_kernel<<<N_ROIS * NBIN, 64, 0, stream>>>(features, rois, out);
    }
}

// Round 8
// 151.247 us; speedup vs baseline: 1.6233x; 1.0225x over previous
//
#include <hip/hip_runtime.h>
#include <hip/hip_bf16.h>

// Problem constants (from reference setup_inputs)
constexpr int B_ = 2, C_ = 256, H_ = 200, W_ = 200;
constexpr int HW_ = H_ * W_;            // 40000
constexpr int N_ROIS = 512;
constexpr int OUT_H_ = 7, OUT_W_ = 7;
constexpr float SPATIAL_SCALE_ = 0.25f;
constexpr int NBIN = OUT_H_ * OUT_W_;   // 49
constexpr int OUT_PER_ROI = C_ * NBIN;  // 12544 floats
constexpr int PIX = C_ / 8;             // uint4 per pixel row in ch-last = 32
constexpr int PTILES = HW_ / 64;        // 625 pixel tiles

using f32x4 = __attribute__((ext_vector_type(4))) float;

__device__ __forceinline__ float bf_lo(unsigned u) {
    const unsigned v = u << 16;
    return __builtin_bit_cast(float, v);
}
__device__ __forceinline__ float bf_hi(unsigned u) {
    const unsigned v = u & 0xffff0000u;
    return __builtin_bit_cast(float, v);
}
__device__ __forceinline__ unsigned bf_pack(float a, float b) {
    __hip_bfloat16 ha = __float2bfloat16(a);
    __hip_bfloat16 hb = __float2bfloat16(b);
    return (unsigned)*(unsigned short*)&ha |
           ((unsigned)*(unsigned short*)&hb << 16);
}

// ---------------------------------------------------------------------------
// Kernel 1: transpose+quantize (B, C, H, W) f32 -> (B, H*W, C) bf16,
// with the ROI rank-sort folded into one extra block (runs concurrently on
// one CU while 5000 transpose blocks saturate the chip -> sort is free).
// Transpose: tile 64 px x 64 ch, block 256; float4 nontemporal loads,
// uint4 (8 bf16) stores. LDS pitch 65 keeps both phases conflict-free.
// ---------------------------------------------------------------------------
__global__ __launch_bounds__(256) void transpose_bf_kernel(
    const float* __restrict__ in, __hip_bfloat16* __restrict__ out,
    const float* __restrict__ rois, int* __restrict__ perm) {
    const int tid = threadIdx.x;

    if (blockIdx.x == PTILES) {
        // ---- sort block: rank-sort 512 ROIs by (batch, y, x) ----
        if (blockIdx.y != 0 || blockIdx.z != 0 || perm == nullptr) return;
        __shared__ unsigned s_key[N_ROIS];
#pragma unroll
        for (int i = tid; i < N_ROIS; i += 256) {
            const float* roi = rois + (size_t)i * 6;
            const int b  = (int)roi[0];
            const int ix = (int)(roi[1] * SPATIAL_SCALE_) & 255;
            const int iy = (int)(roi[2] * SPATIAL_SCALE_) & 255;
            s_key[i] = ((unsigned)b << 16) | ((unsigned)iy << 8) | (unsigned)ix;
        }
        __syncthreads();
#pragma unroll
        for (int i = tid; i < N_ROIS; i += 256) {
            const unsigned key = s_key[i];
            int rank = 0;
            for (int j = 0; j < N_ROIS; ++j) {
                const unsigned kj = s_key[j];
                rank += (kj < key) || (kj == key && j < i);
            }
            perm[rank] = i;
        }
        return;
    }

    // ---- transpose blocks ----
    __shared__ float tile[64][65];
    const int b  = blockIdx.z;
    const int p0 = blockIdx.x * 64;   // pixel tile origin
    const int c0 = blockIdx.y * 64;   // channel tile origin
    const int hi = tid >> 4;          // 0..15
    const int lo = tid & 15;          // 0..15

    const float* src = in + (size_t)b * C_ * HW_;
    __hip_bfloat16* dst = out + (size_t)b * HW_ * C_;

#pragma unroll
    for (int j = 0; j < 4; ++j) {
        const int cr = hi + j * 16;             // channel within tile
        const int pm = lo * 4;                  // pixel within tile
        const f32x4 v = __builtin_nontemporal_load(
            (const f32x4*)(src + (size_t)(c0 + cr) * HW_ + p0 + pm));
        tile[pm + 0][cr] = v.x;
        tile[pm + 1][cr] = v.y;
        tile[pm + 2][cr] = v.z;
        tile[pm + 3][cr] = v.w;
    }
    __syncthreads();
#pragma unroll
    for (int j = 0; j < 2; ++j) {
        const int pr = (tid >> 3) + j * 32;     // pixel within tile 0..63
        const int cm = 8 * (tid & 7);           // channel within tile
        uint4 u;
        u.x = bf_pack(tile[pr][cm + 0], tile[pr][cm + 1]);
        u.y = bf_pack(tile[pr][cm + 2], tile[pr][cm + 3]);
        u.z = bf_pack(tile[pr][cm + 4], tile[pr][cm + 5]);
        u.w = bf_pack(tile[pr][cm + 6], tile[pr][cm + 7]);
        *(uint4*)(dst + (size_t)(p0 + pr) * C_ + c0 + cm) = u;
    }
}

// ---------------------------------------------------------------------------
// Kernel 2: rotated ROI align from bf16 channels-last features.
// One 512-thread block per ROI (grid 512 = exactly 2 blocks/CU).
// Half-wave hw = tid>>5 owns bins {hw, hw+16, ...}; lane cl = tid&31 owns
// 8 adjacent channels -> each corner is ONE uint4 load (512 B/half-wave).
// s_off holds pre-scaled uint4 offsets (no mul in inner loop).
// XCD-chunked swizzle over sorted perm keeps each XCD on 64 adjacent ROIs.
// ---------------------------------------------------------------------------
__global__ __launch_bounds__(512, 4) void rroi_gather_kernel(
    const __hip_bfloat16* __restrict__ feat,   // (B, H*W, C) bf16
    const float* __restrict__ rois,
    const int* __restrict__ perm,              // may be nullptr
    float* __restrict__ out) {
    __shared__ float  s_out[OUT_PER_ROI];   // 50176 B, [c][bin] pitch 49
    __shared__ int    s_off[196];           // (y0*W + x0) * PIX
    __shared__ float4 s_w[196];

    const int bid  = blockIdx.x;
    const int slot = (bid & 7) * 64 + (bid >> 3);    // XCD-chunked
    const int n    = perm ? perm[slot] : slot;
    const int tid  = threadIdx.x;

    const float* roi = rois + (size_t)n * 6;
    const int   b     = (int)roi[0];
    const float cx    = roi[1] * SPATIAL_SCALE_;
    const float cy    = roi[2] * SPATIAL_SCALE_;
    const float rw    = fmaxf(roi[3] * SPATIAL_SCALE_, 1.0f);
    const float rh    = fmaxf(roi[4] * SPATIAL_SCALE_, 1.0f);
    const float theta = roi[5];
    const float bin_h = rh / (float)OUT_H_;
    const float bin_w = rw / (float)OUT_W_;

    if (tid < 196) {
        const float cosT = cosf(theta);
        const float sinT = sinf(theta);
        const int bin = tid >> 2;
        const int s   = tid & 3;
        const int ph  = bin / OUT_W_;
        const int pw  = bin - ph * OUT_W_;
        const int s1  = s >> 1;
        const int s2  = s & 1;

        const float yy = -rh * 0.5f + ((float)ph + ((float)s1 + 0.5f) * 0.5f) * bin_h;
        const float xx = -rw * 0.5f + ((float)pw + ((float)s2 + 0.5f) * 0.5f) * bin_w;

        float x = xx * cosT + yy * sinT + cx;
        float y = yy * cosT - xx * sinT + cy;

        const bool valid = (y > -1.0f) && (y < (float)H_) &&
                           (x > -1.0f) && (x < (float)W_);

        y = fminf(fmaxf(y, 0.0f), (float)(H_ - 1));
        x = fminf(fmaxf(x, 0.0f), (float)(W_ - 1));
        int y0 = (int)floorf(y);  if (y0 > H_ - 2) y0 = H_ - 2;
        int x0 = (int)floorf(x);  if (x0 > W_ - 2) x0 = W_ - 2;

        const float ly = y - (float)y0;
        const float lx = x - (float)x0;
        const float hy = 1.0f - ly;
        const float hx = 1.0f - lx;
        const float m  = valid ? 0.25f : 0.0f;   // fold mean + validity

        s_w[tid]   = make_float4(hy * hx * m, hy * lx * m, ly * hx * m, ly * lx * m);
        s_off[tid] = (y0 * W_ + x0) * PIX;
    }
    __syncthreads();

    const int hw = tid >> 5;             // half-wave id 0..15
    const int cl = tid & 31;             // channel-octet id
    const uint4* base = (const uint4*)(feat + (size_t)b * HW_ * C_) + cl;

    for (int bin = hw; bin < NBIN; bin += 16) {
        float acc[8] = {0.f, 0.f, 0.f, 0.f, 0.f, 0.f, 0.f, 0.f};
#pragma unroll
        for (int s = 0; s < 4; ++s) {
            const int j = bin * 4 + s;
            const float4 w = s_w[j];
            const uint4* p = base + s_off[j];
            const uint4 u00 = p[0];
            const uint4 u01 = p[PIX];
            const uint4 u10 = p[W_ * PIX];
            const uint4 u11 = p[W_ * PIX + PIX];

            acc[0] += w.x * bf_lo(u00.x) + w.y * bf_lo(u01.x) +
                      w.z * bf_lo(u10.x) + w.w * bf_lo(u11.x);
            acc[1] += w.x * bf_hi(u00.x) + w.y * bf_hi(u01.x) +
                      w.z * bf_hi(u10.x) + w.w * bf_hi(u11.x);
            acc[2] += w.x * bf_lo(u00.y) + w.y * bf_lo(u01.y) +
                      w.z * bf_lo(u10.y) + w.w * bf_lo(u11.y);
            acc[3] += w.x * bf_hi(u00.y) + w.y * bf_hi(u01.y) +
                      w.z * bf_hi(u10.y) + w.w * bf_hi(u11.y);
            acc[4] += w.x * bf_lo(u00.z) + w.y * bf_lo(u01.z) +
                      w.z * bf_lo(u10.z) + w.w * bf_lo(u11.z);
            acc[5] += w.x * bf_hi(u00.z) + w.y * bf_hi(u01.z) +
                      w.z * bf_hi(u10.z) + w.w * bf_hi(u11.z);
            acc[6] += w.x * bf_lo(u00.w) + w.y * bf_lo(u01.w) +
                      w.z * bf_lo(u10.w) + w.w * bf_lo(u11.w);
            acc[7] += w.x * bf_hi(u00.w) + w.y * bf_hi(u01.w) +
                      w.z * bf_hi(u10.w) + w.w * bf_hi(u11.w);
        }
        const int c = 8 * cl;
#pragma unroll
        for (int i = 0; i < 8; ++i) {
            s_out[(c + i) * NBIN + bin] = acc[i];
        }
    }
    __syncthreads();

    // Flush: 12544 floats = 3136 float4 = 6*512 + 64; nontemporal (no reuse).
    f32x4* o = (f32x4*)(out + (size_t)n * OUT_PER_ROI);
    const f32x4* l = (const f32x4*)s_out;
#pragma unroll
    for (int k = 0; k < 6; ++k) {
        __builtin_nontemporal_store(l[tid + 512 * k], o + tid + 512 * k);
    }
    if (tid < 64) __builtin_nontemporal_store(l[3072 + tid], o + 3072 + tid);
}

// ---------------------------------------------------------------------------
// Fallback (channels-first f32, scalar) — only if ws too small.
// ---------------------------------------------------------------------------
__global__ __launch_bounds__(64) void rroi_fallback_kernel(
    const float* __restrict__ feat,
    const float* __restrict__ rois,
    float* __restrict__ out) {
    const int blk = blockIdx.x;
    const int n   = blk / NBIN;
    const int bin = blk % NBIN;
    const int ph  = bin / OUT_W_;
    const int pw  = bin % OUT_W_;

    const float* roi = rois + (size_t)n * 6;
    const int   b     = (int)roi[0];
    const float cx    = roi[1] * SPATIAL_SCALE_;
    const float cy    = roi[2] * SPATIAL_SCALE_;
    const float rw    = fmaxf(roi[3] * SPATIAL_SCALE_, 1.0f);
    const float rh    = fmaxf(roi[4] * SPATIAL_SCALE_, 1.0f);
    const float theta = roi[5];
    const float bin_h = rh / (float)OUT_H_;
    const float bin_w = rw / (float)OUT_W_;
    const float cosT  = cosf(theta);
    const float sinT  = sinf(theta);
    const int t = threadIdx.x;
    float acc[4] = {0.f, 0.f, 0.f, 0.f};

#pragma unroll
    for (int s1 = 0; s1 < 2; ++s1) {
        const float yy = -rh * 0.5f + ((float)ph + ((float)s1 + 0.5f) * 0.5f) * bin_h;
#pragma unroll
        for (int s2 = 0; s2 < 2; ++s2) {
            const float xx = -rw * 0.5f + ((float)pw + ((float)s2 + 0.5f) * 0.5f) * bin_w;
            float x = xx * cosT + yy * sinT + cx;
            float y = yy * cosT - xx * sinT + cy;
            const bool valid = (y > -1.0f) && (y < (float)H_) &&
                               (x > -1.0f) && (x < (float)W_);
            if (!valid) continue;
            y = fminf(fmaxf(y, 0.0f), (float)(H_ - 1));
            x = fminf(fmaxf(x, 0.0f), (float)(W_ - 1));
            int y0 = (int)floorf(y);  if (y0 > H_ - 2) y0 = H_ - 2;
            int x0 = (int)floorf(x);  if (x0 > W_ - 2) x0 = W_ - 2;
            const float ly = y - (float)y0, lx = x - (float)x0;
            const float hy = 1.0f - ly, hx = 1.0f - lx;
            const float w00 = hy * hx, w01 = hy * lx, w10 = ly * hx, w11 = ly * lx;
            const int off0 = y0 * W_ + x0;
#pragma unroll
            for (int i = 0; i < 4; ++i) {
                const float* basep = feat + ((size_t)b * C_ + 4 * t + i) * HW_;
                acc[i] += w00 * basep[off0] + w01 * basep[off0 + 1] +
                          w10 * basep[off0 + W_] + w11 * basep[off0 + W_ + 1];
            }
        }
    }
#pragma unroll
    for (int i = 0; i < 4; ++i) {
        out[((size_t)n * C_ + (4 * t + i)) * NBIN + bin] = acc[i] * 0.25f;
    }
}

extern "C" void kernel_launch(void* const* d_in, const int* in_sizes, int n_in,
                              void* d_out, int out_size, void* d_ws, size_t ws_size,
                              hipStream_t stream) {
    const float* features = (const float*)d_in[0];  // (B, C, H, W)
    const float* rois     = (const float*)d_in[1];  // (N, 6)
    float* out = (float*)d_out;                     // (N, C, 7, 7)

    const size_t feat_bytes = (size_t)B_ * C_ * HW_ * sizeof(__hip_bfloat16); // 40.96 MB
    const size_t perm_bytes = (size_t)N_ROIS * sizeof(int);

    if (ws_size >= feat_bytes + 256 + perm_bytes) {
        __hip_bfloat16* feat_bf = (__hip_bfloat16*)d_ws;
        int* perm = (int*)((char*)d_ws + ((feat_bytes + 255) & ~(size_t)255));
        dim3 tg(PTILES + 1, C_ / 64, B_);   // extra x-column hosts the sort
        transpose_bf_kernel<<<tg, 256, 0, stream>>>(features, feat_bf, rois, perm);
        rroi_gather_kernel<<<N_ROIS, 512, 0, stream>>>(feat_bf, rois, perm, out);
    } else if (ws_size >= feat_bytes) {
        __hip_bfloat16* feat_bf = (__hip_bfloat16*)d_ws;
        dim3 tg(PTILES + 1, C_ / 64, B_);
        transpose_bf_kernel<<<tg, 256, 0, stream>>>(features, feat_bf, rois, nullptr);
        rroi_gather_kernel<<<N_ROIS, 512, 0, stream>>>(feat_bf, rois, nullptr, out);
    } else {
        rroi_fallback_kernel<<<N_ROIS * NBIN, 64, 0, stream>>>(features, rois, out);
    }
}